// Round 13
// baseline (175.461 us; speedup 1.0000x reference)
//
#include <hip/hip_runtime.h>
#include <hip/hip_fp16.h>

// ---------- types ----------
typedef __attribute__((ext_vector_type(8))) _Float16 f16x8;
typedef __attribute__((ext_vector_type(4))) float f32x4;

typedef const __attribute__((address_space(1))) void gas_void;
typedef __attribute__((address_space(3))) void las_void;
typedef __attribute__((address_space(3))) const __half las_chalf;

// asm ds_read_b128: opaque to the compiler's waitcnt pass (we manage lgkmcnt)
__device__ __forceinline__ f16x8 ldsr(const __half* p) {
    f16x8 r;
    asm volatile("ds_read_b128 %0, %1" : "=v"(r) : "v"((las_chalf*)p));
    return r;
}

// ---------- threefry2x32, JAX PARTITIONABLE variant ----------
__device__ __forceinline__ uint32_t rotl32(uint32_t x, int d) { return (x << d) | (x >> (32 - d)); }

__device__ __forceinline__ bool keep_bit(uint32_t flat) {
    uint32_t x0 = 0u;
    uint32_t x1 = flat;
    const uint32_t ks0 = 0u, ks1 = 42u, ks2 = 0u ^ 42u ^ 0x1BD11BDAu;
    x0 += ks0; x1 += ks1;
#define TFR(r) { x0 += x1; x1 = rotl32(x1, r); x1 ^= x0; }
    TFR(13) TFR(15) TFR(26) TFR(6)   x0 += ks1; x1 += ks2 + 1u;
    TFR(17) TFR(29) TFR(16) TFR(24)  x0 += ks2; x1 += ks0 + 2u;
    TFR(13) TFR(15) TFR(26) TFR(6)   x0 += ks0; x1 += ks1 + 3u;
    TFR(17) TFR(29) TFR(16) TFR(24)  x0 += ks1; x1 += ks2 + 4u;
    TFR(13) TFR(15) TFR(26) TFR(6)   x0 += ks2; x1 += ks0 + 5u;
#undef TFR
    uint32_t bits = x0 ^ x1;
    float u = __uint_as_float((bits >> 9) | 0x3f800000u) - 1.0f;
    return u < 0.9f;
}

// ---------- all input casts f32 -> f16 in one dispatch (grid 3584) ----------
__global__ __launch_bounds__(256) void cast_all_k(const float* __restrict__ x,
                                                  const float* __restrict__ wq,
                                                  const float* __restrict__ wk,
                                                  const float* __restrict__ wv,
                                                  __half* __restrict__ xb,
                                                  __half* __restrict__ wqkv) {
    const int b = blockIdx.x;
    const float* src;
    __half* dst;
    size_t i;
    if (b < 2048) {
        src = x; dst = xb;
        i = ((size_t)b * 256 + threadIdx.x) * 8;
    } else {
        const int w = (b - 2048) >> 9;
        src = w == 0 ? wq : (w == 1 ? wk : wv);
        dst = wqkv + (size_t)w * 1048576;
        i = (((size_t)((b - 2048) & 511)) * 256 + threadIdx.x) * 8;
    }
    float4 a = *(const float4*)(src + i);
    float4 c = *(const float4*)(src + i + 4);
    __half2 h[4] = { __floats2half2_rn(a.x, a.y), __floats2half2_rn(a.z, a.w),
                     __floats2half2_rn(c.x, c.y), __floats2half2_rn(c.z, c.w) };
    *(int4*)(dst + i) = *(int4*)h;
}

// ============================================================================
// 256x256 8-phase GEMM engine (T1+T2+T3+T4+T5), C = scale * A @ B^T, f16 in.
// 8 waves (2M x 4N), BK=64, LDS 128KB dynamic: [buf(2)][mat(2)][256][64] f16.
// MODE 0 (QKVT): grid 192. sw<128: QK proj (ld 2048); sw>=128: VT = wv @ x^T.
// MODE 1 (S)   : grid 256. id<136: triangular GEMM (diag blocks zero col>row);
//                id>=136: 120 mask-gen blocks (threefry dropout mask, 1b/elem).
// MODE 2 (PV)  : grid 196, balanced causal split-K, chunks <=13 tiles;
//                chunk 0 -> out (rows<768 scaled), chunks 1..4 -> f16 PH1..PH4.
// ============================================================================
template <int MODE>
__global__ __launch_bounds__(512, 2)
void gemm256(const __half* __restrict__ pA, const __half* __restrict__ pB,
             void* __restrict__ pC, void* __restrict__ pC2,
             __half* __restrict__ PH1, __half* __restrict__ PH2,
             __half* __restrict__ PH3, __half* __restrict__ PH4,
             const float* __restrict__ Lr, unsigned char* __restrict__ mask) {
    constexpr int LD = (MODE == 0) ? 1024 : (MODE == 1 ? 2048 : 4096);

    const int tid = threadIdx.x;

    int bi, bj, c = 0, k_lo = 0, NT = 16;
    bool isVT = false;
    if constexpr (MODE == 0) {
        const int id = blockIdx.x;
        const int sw = (id & 7) * 24 + (id >> 3);          // 192 = 8*24, bijective
        if (sw < 128) { bi = sw >> 3; bj = sw & 7; }
        else          { int s2 = sw - 128; bi = s2 >> 4; bj = s2 & 15; isVT = true; }
    } else if constexpr (MODE == 1) {
        const int id = blockIdx.x;
        if (id >= 136) {
            // ---- dropout mask generation on the 120 otherwise-idle CUs ----
            const int mid = id - 136;                       // 0..119
            for (int pr = mid; pr < 2048; pr += 120) {
                const int ra = pr;                          // short row
                const int rb = 4095 - pr;                   // long row
                const int nba = (ra >> 3) + 1;              // bytes covering len=ra+1
                const int nbb = (rb >> 3) + 1;
                const int tot = nba + nbb;
                for (int t = tid; t < tot; t += 512) {
                    int row, b0;
                    if (t < nba) { row = ra; b0 = t << 3; }
                    else         { row = rb; b0 = (t - nba) << 3; }
                    const uint32_t base = (uint32_t)row * 4096u + (uint32_t)b0;
                    uint32_t bits = 0;
#pragma unroll
                    for (int q = 0; q < 8; ++q)
                        bits |= (keep_bit(base + q) ? 1u : 0u) << q;
                    mask[(size_t)row * 512 + (b0 >> 3)] = (unsigned char)bits;
                }
            }
            return;
        }
        const int sw = (id & 7) * 17 + (id >> 3);          // 136 = 8*17
        int b = (int)((sqrtf(8.0f * sw + 1.0f) - 1.0f) * 0.5f);
        while ((b + 1) * (b + 2) / 2 <= sw) ++b;
        while (b * (b + 1) / 2 > sw) --b;
        bi = b; bj = sw - b * (b + 1) / 2;
    } else {
        // m204 bijective XCD swizzle over 196 blocks (196 = 4*25 + 4*24)
        const int id = blockIdx.x;
        const int xcd = id & 7;
        const int sw = (xcd < 4 ? xcd * 25 : 100 + (xcd - 4) * 24) + (id >> 3);
        bj = sw / 49;
        int x = sw - 49 * bj;
        int nch = 1;
        for (bi = 0; bi < 16; ++bi) {
            nch = (4 * (bi + 1) + 12) / 13;
            if (x < nch) { c = x; break; }
            x -= nch;
        }
        const int full = 4 * (bi + 1);
        k_lo = c * 13;
        NT = min(full - k_lo, 13);
    }

    const __half* A = pA;
    const __half* B = pB;
    if constexpr (MODE == 0) {
        if (isVT) { A = pB + 2097152; B = pA; }   // A = wv (rows 2048.. of wqkv), B = x
    }

    const int brow = bi * 256, bcol = bj * 256;
    const int lane = tid & 63, wid = tid >> 6;
    const int wm = wid >> 2, wn = wid & 3;
    const int lane15 = lane & 15;
    const int kxor = (lane & 7) << 3;
    const int g16 = (lane >> 4) << 3;

    extern __shared__ __half smem[];  // [2][2][256*64]

    const int srow = (wid << 3) + (lane >> 3);                 // 0..63
    const int scol = ((lane & 7) ^ ((lane >> 3) & 7)) << 3;    // swizzled source col

    auto stage_half = [&](const __half* G, int growbase, int kt, int buf, int mat, int half) {
        const __half* src = G + (size_t)(growbase + half * 128 + srow) * LD + kt * 64 + scol;
        __half* dst = &smem[buf * 32768 + mat * 16384 + (half * 128 + (wid << 3)) * 64];
        __builtin_amdgcn_global_load_lds((gas_void*)src, (las_void*)dst, 16, 0, 0);
        __builtin_amdgcn_global_load_lds((gas_void*)(src + (size_t)64 * LD),
                                         (las_void*)(dst + 64 * 64), 16, 0, 0);
    };

    f32x4 acc[8][4] = {};
    f16x8 bfrag[2][4];

    // prologue: tile k_lo {Ba,Bb,Aa,Ab} + tile k_lo+1 {Ba,Bb}
    stage_half(B, bcol, k_lo, 0, 1, 0);
    stage_half(B, bcol, k_lo, 0, 1, 1);
    stage_half(A, brow, k_lo, 0, 0, 0);
    stage_half(A, brow, k_lo, 0, 0, 1);
    if (NT > 1) {
        stage_half(B, bcol, k_lo + 1, 1, 1, 0);
        stage_half(B, bcol, k_lo + 1, 1, 1, 1);
    }

    for (int Tr = 0; Tr < NT; ++Tr) {
        const int Ta = k_lo + Tr;
        const int buf = Tr & 1;
        const __half* Abase = &smem[buf * 32768 + (wm * 128 + lane15) * 64];
        const __half* Bbase = &smem[buf * 32768 + 16384 + (wn * 64 + lane15) * 64];

        // ---- phase 0 ----
        if (Tr < NT - 1) asm volatile("s_waitcnt vmcnt(4)" ::: "memory");
        else             asm volatile("s_waitcnt vmcnt(0)" ::: "memory");
        __builtin_amdgcn_s_barrier();   // tile Tr fully resident for all waves

        {
#pragma unroll
            for (int kk = 0; kk < 2; ++kk)
#pragma unroll
                for (int n = 0; n < 4; ++n)
                    bfrag[kk][n] = ldsr(Bbase + (n * 16) * 64 + ((kk * 32 + g16) ^ kxor));
            f16x8 af[2][2];
#pragma unroll
            for (int mi = 0; mi < 2; ++mi)
#pragma unroll
                for (int kk = 0; kk < 2; ++kk)
                    af[mi][kk] = ldsr(Abase + (mi * 16) * 64 + ((kk * 32 + g16) ^ kxor));
            if (Tr + 1 < NT) stage_half(A, brow, Ta + 1, buf ^ 1, 0, 0);
            asm volatile("s_waitcnt lgkmcnt(0)" ::: "memory");
            __builtin_amdgcn_sched_barrier(0);
            __builtin_amdgcn_s_setprio(1);
#pragma unroll
            for (int mi = 0; mi < 2; ++mi)
#pragma unroll
                for (int n = 0; n < 4; ++n)
#pragma unroll
                    for (int kk = 0; kk < 2; ++kk)
                        acc[mi][n] = __builtin_amdgcn_mfma_f32_16x16x32_f16(
                            af[mi][kk], bfrag[kk][n], acc[mi][n], 0, 0, 0);
            __builtin_amdgcn_s_setprio(0);
            __builtin_amdgcn_s_barrier();
        }

        // ---- phases 1..3 ----
#pragma unroll
        for (int p = 1; p < 4; ++p) {
            f16x8 af[2][2];
#pragma unroll
            for (int mi = 0; mi < 2; ++mi)
#pragma unroll
                for (int kk = 0; kk < 2; ++kk)
                    af[mi][kk] = ldsr(Abase + ((2 * p + mi) * 16) * 64 + ((kk * 32 + g16) ^ kxor));
            if (p == 1)      { if (Tr + 1 < NT) stage_half(A, brow, Ta + 1, buf ^ 1, 0, 1); }
            else if (p == 2) { if (Tr + 2 < NT) stage_half(B, bcol, Ta + 2, buf, 1, 0); }
            else             { if (Tr + 2 < NT) stage_half(B, bcol, Ta + 2, buf, 1, 1); }
            asm volatile("s_waitcnt lgkmcnt(0)" ::: "memory");
            __builtin_amdgcn_sched_barrier(0);
            __builtin_amdgcn_s_setprio(1);
#pragma unroll
            for (int mi = 0; mi < 2; ++mi)
#pragma unroll
                for (int n = 0; n < 4; ++n)
#pragma unroll
                    for (int kk = 0; kk < 2; ++kk)
                        acc[2 * p + mi][n] = __builtin_amdgcn_mfma_f32_16x16x32_f16(
                            af[mi][kk], bfrag[kk][n], acc[2 * p + mi][n], 0, 0, 0);
            __builtin_amdgcn_s_setprio(0);
            __builtin_amdgcn_s_barrier();
        }
    }

    // ---- epilogue ----
    const int r0 = (lane >> 4) << 2;
    if constexpr (MODE == 2) {
        if (c == 0) {
            float* Ct = (float*)pC;
            const bool doScale = (4 * (bi + 1) <= 13);   // single-chunk rows (bi<=2)
#pragma unroll
            for (int m = 0; m < 8; ++m)
#pragma unroll
                for (int r = 0; r < 4; ++r) {
                    const int row = brow + wm * 128 + m * 16 + r0 + r;
                    const float inv = doScale ? 1.0f / (0.9f * Lr[row]) : 1.0f;
#pragma unroll
                    for (int n = 0; n < 4; ++n) {
                        const int col = bcol + wn * 64 + n * 16 + lane15;
                        Ct[(size_t)row * 1024 + col] = acc[m][n][r] * inv;
                    }
                }
        } else {
            __half* Ph = (c == 1) ? PH1 : (c == 2 ? PH2 : (c == 3 ? PH3 : PH4));
#pragma unroll
            for (int m = 0; m < 8; ++m)
#pragma unroll
                for (int n = 0; n < 4; ++n) {
                    const int col = bcol + wn * 64 + n * 16 + lane15;
#pragma unroll
                    for (int r = 0; r < 4; ++r) {
                        const int row = brow + wm * 128 + m * 16 + r0 + r;
                        Ph[(size_t)row * 1024 + col] = __float2half(acc[m][n][r]);
                    }
                }
        }
    } else {
        __half* Ct = (__half*)pC;
        int ldc = (MODE == 1) ? 4096 : 2048;
        const float scl = (MODE == 1) ? 0.03125f : 1.0f;
        if constexpr (MODE == 0) {
            if (isVT) { Ct = (__half*)pC2; ldc = 4096; }
        }
        const bool dz = (MODE == 1) && (bi == bj);   // diag block: zero col > row
#pragma unroll
        for (int m = 0; m < 8; ++m)
#pragma unroll
            for (int n = 0; n < 4; ++n) {
                const int col = bcol + wn * 64 + n * 16 + lane15;
#pragma unroll
                for (int r = 0; r < 4; ++r) {
                    const int row = brow + wm * 128 + m * 16 + r0 + r;
                    float v = acc[m][n][r] * scl;
                    if (dz && col > row) v = 0.0f;
                    Ct[(size_t)row * ldc + col] = __float2half(v);
                }
            }
    }
}

// ---------- split-K merge (rows >= 768) + deferred softmax scaling ----------
__global__ __launch_bounds__(256) void pv_merge_k(float* __restrict__ out,
                                                  const __half* __restrict__ PH1,
                                                  const __half* __restrict__ PH2,
                                                  const __half* __restrict__ PH3,
                                                  const __half* __restrict__ PH4,
                                                  const float* __restrict__ L) {
    const int row = 768 + blockIdx.x;
    const int bi = row >> 8;
    const int nch = (4 * (bi + 1) + 12) / 13;
    const float inv = 1.0f / (0.9f * L[row]);
    const size_t o = (size_t)row * 1024 + threadIdx.x * 4;
    float4 s = *(float4*)(out + o);
    const __half* planes[4] = { PH1, PH2, PH3, PH4 };
#pragma unroll 4
    for (int cc = 1; cc < nch; ++cc) {
        const __half2* p2 = (const __half2*)(planes[cc - 1] + o);
        float2 a = __half22float2(p2[0]);
        float2 b = __half22float2(p2[1]);
        s.x += a.x; s.y += a.y; s.z += b.x; s.w += b.y;
    }
    s.x *= inv; s.y *= inv; s.z *= inv; s.w *= inv;
    *(float4*)(out + o) = s;
}

// ---------- single-sweep deferred softmax using precomputed mask ----------
// P' = mask * exp(S) (M=0), L[row] = sum(exp). Band above diagonal already
// zeroed by the S-GEMM epilogue.
__global__ __launch_bounds__(256) void softdrop_k(__half* __restrict__ SP,
                                                  float* __restrict__ L,
                                                  const unsigned char* __restrict__ mask,
                                                  int N) {
    const int i = blockIdx.x;
    const int tid = threadIdx.x;
    const int len = i + 1;
    __half* row = SP + (size_t)i * N;
    const unsigned char* mrow = mask + (size_t)i * 512;

    float l = 0.f;
    const int len8 = len & ~7;
    for (int j = tid * 8; j < len8; j += 2048) {
        int4 pk = *(const int4*)(row + j);
        const __half* hp = (const __half*)&pk;
        const unsigned int mb = mrow[j >> 3];
        __half o8[8];
#pragma unroll
        for (int q = 0; q < 8; ++q) {
            float e = __expf(__half2float(hp[q]));
            l += e;
            o8[q] = ((mb >> q) & 1u) ? __float2half(e) : __float2half(0.0f);
        }
        *(int4*)(row + j) = *(int4*)o8;
    }
    for (int j = len8 + tid; j < len; j += 256) {
        float e = __expf(__half2float(row[j]));
        l += e;
        row[j] = ((mrow[j >> 3] >> (j & 7)) & 1u) ? __float2half(e) : __float2half(0.0f);
    }

    for (int off = 1; off < 64; off <<= 1) l += __shfl_xor(l, off);
    __shared__ float ls[4];
    if ((tid & 63) == 0) ls[tid >> 6] = l;
    __syncthreads();
    if (tid == 0) L[i] = ls[0] + ls[1] + ls[2] + ls[3];
}

// ---------- launch ----------
extern "C" void kernel_launch(void* const* d_in, const int* in_sizes, int n_in,
                              void* d_out, int out_size, void* d_ws, size_t ws_size,
                              hipStream_t stream) {
    const float* x  = (const float*)d_in[0];
    const float* wq = (const float*)d_in[1];
    const float* wk = (const float*)d_in[2];
    const float* wv = (const float*)d_in[3];
    float* out = (float*)d_out;
    char* ws = (char*)d_ws;

    const int N = 4096;

    __half* xb   = (__half*)(ws + 0);          // 4096x1024   (8 MB)
    __half* wqkv = (__half*)(ws + 8388608);    // 3072x1024   (6 MB)
    __half* QK   = (__half*)(ws + 14680064);   // 4096x2048   (16 MB), ld=2048
    __half* VT   = (__half*)(ws + 31457280);   // 1024x4096   (8 MB),  ld=4096
    __half* SP   = (__half*)(ws + 48234496);   // 4096x4096   (32 MB)
    float*  Lr   = (float*)(ws + 81788928);    // 4096 f32    (16 KB)
    __half* PH1  = (__half*)(ws + 83886080);   // 4096x1024 f16 (8 MB)
    __half* PH2  = (__half*)(ws + 92274688);
    __half* PH3  = (__half*)(ws + 100663296);
    __half* PH4  = (__half*)(ws + 109051904);  // end 117440512
    unsigned char* mask8 = (unsigned char*)(ws + 117440512);  // 4096x512 B (2 MB)

    __half* Q = QK;             // ld = 2048
    __half* K = QK + 1024;

    auto* g0 = gemm256<0>;
    auto* g1 = gemm256<1>;
    auto* g2 = gemm256<2>;
    (void)hipFuncSetAttribute((const void*)g0, hipFuncAttributeMaxDynamicSharedMemorySize, 131072);
    (void)hipFuncSetAttribute((const void*)g1, hipFuncAttributeMaxDynamicSharedMemorySize, 131072);
    (void)hipFuncSetAttribute((const void*)g2, hipFuncAttributeMaxDynamicSharedMemorySize, 131072);

    cast_all_k<<<3584, 256, 0, stream>>>(x, wq, wk, wv, xb, wqkv);

    // QK projection + native V^T (= wv @ x^T), one dispatch, 192 blocks
    g0<<<192, 512, 131072, stream>>>(xb, wqkv, QK, VT, nullptr, nullptr, nullptr, nullptr,
                                     nullptr, nullptr);

    // S = Q @ K^T * (1/32): 136 triangular GEMM blocks + 120 mask-gen blocks
    g1<<<256, 512, 131072, stream>>>(Q, K, SP, nullptr, nullptr, nullptr, nullptr, nullptr,
                                     nullptr, mask8);

    // single sweep: P' = mask * exp(S), L[row] = sum exp(S)
    softdrop_k<<<N, 256, 0, stream>>>(SP, Lr, mask8, N);

    // PV: balanced causal split-K, 196 blocks (chunks <= 13 tiles, f16 partials)
    g2<<<196, 512, 131072, stream>>>(SP, VT, out, nullptr, PH1, PH2, PH3, PH4, Lr, nullptr);

    // merge partials + apply 1/(0.9*L) for rows >= 768
    pv_merge_k<<<3328, 256, 0, stream>>>(out, PH1, PH2, PH3, PH4, Lr);
}

// Round 14
// 140.761 us; speedup vs baseline: 1.2465x; 1.2465x over previous
//
#include <hip/hip_runtime.h>
#include <hip/hip_fp16.h>

// ---------- types ----------
typedef __attribute__((ext_vector_type(8))) _Float16 f16x8;
typedef __attribute__((ext_vector_type(4))) float f32x4;

typedef const __attribute__((address_space(1))) void gas_void;
typedef __attribute__((address_space(3))) void las_void;
typedef __attribute__((address_space(3))) const __half las_chalf;

// asm ds_read_b128: opaque to the compiler's waitcnt pass (we manage lgkmcnt)
__device__ __forceinline__ f16x8 ldsr(const __half* p) {
    f16x8 r;
    asm volatile("ds_read_b128 %0, %1" : "=v"(r) : "v"((las_chalf*)p));
    return r;
}

// ---------- threefry2x32, JAX PARTITIONABLE variant ----------
__device__ __forceinline__ uint32_t rotl32(uint32_t x, int d) { return (x << d) | (x >> (32 - d)); }

__device__ __forceinline__ bool keep_bit(uint32_t flat) {
    uint32_t x0 = 0u;
    uint32_t x1 = flat;
    const uint32_t ks0 = 0u, ks1 = 42u, ks2 = 0u ^ 42u ^ 0x1BD11BDAu;
    x0 += ks0; x1 += ks1;
#define TFR(r) { x0 += x1; x1 = rotl32(x1, r); x1 ^= x0; }
    TFR(13) TFR(15) TFR(26) TFR(6)   x0 += ks1; x1 += ks2 + 1u;
    TFR(17) TFR(29) TFR(16) TFR(24)  x0 += ks2; x1 += ks0 + 2u;
    TFR(13) TFR(15) TFR(26) TFR(6)   x0 += ks0; x1 += ks1 + 3u;
    TFR(17) TFR(29) TFR(16) TFR(24)  x0 += ks1; x1 += ks2 + 4u;
    TFR(13) TFR(15) TFR(26) TFR(6)   x0 += ks2; x1 += ks0 + 5u;
#undef TFR
    uint32_t bits = x0 ^ x1;
    float u = __uint_as_float((bits >> 9) | 0x3f800000u) - 1.0f;
    return u < 0.9f;
}

// ---------- all input casts f32 -> f16 in one dispatch (grid 3584) ----------
__global__ __launch_bounds__(256) void cast_all_k(const float* __restrict__ x,
                                                  const float* __restrict__ wq,
                                                  const float* __restrict__ wk,
                                                  const float* __restrict__ wv,
                                                  __half* __restrict__ xb,
                                                  __half* __restrict__ wqkv) {
    const int b = blockIdx.x;
    const float* src;
    __half* dst;
    size_t i;
    if (b < 2048) {
        src = x; dst = xb;
        i = ((size_t)b * 256 + threadIdx.x) * 8;
    } else {
        const int w = (b - 2048) >> 9;
        src = w == 0 ? wq : (w == 1 ? wk : wv);
        dst = wqkv + (size_t)w * 1048576;
        i = (((size_t)((b - 2048) & 511)) * 256 + threadIdx.x) * 8;
    }
    float4 a = *(const float4*)(src + i);
    float4 c = *(const float4*)(src + i + 4);
    __half2 h[4] = { __floats2half2_rn(a.x, a.y), __floats2half2_rn(a.z, a.w),
                     __floats2half2_rn(c.x, c.y), __floats2half2_rn(c.z, c.w) };
    *(int4*)(dst + i) = *(int4*)h;
}

// ============================================================================
// 256x256 8-phase GEMM engine (T1+T2+T3+T4+T5), C = scale * A @ B^T, f16 in.
// 8 waves (2M x 4N), BK=64, LDS 128KB dynamic: [buf(2)][mat(2)][256][64] f16.
// MODE 0 (QKVT): grid 192. sw<128: QK proj (ld 2048); sw>=128: VT = wv @ x^T.
// MODE 1 (S)   : grid 136, triangular decode; diag blocks zero col>row.
// MODE 2 (PV)  : grid 196, balanced causal split-K, chunks <=13 tiles;
//                chunk 0 -> out (rows<768 scaled), chunks 1..4 -> f16 PH1..PH4.
// ============================================================================
template <int MODE>
__global__ __launch_bounds__(512, 2)
void gemm256(const __half* __restrict__ pA, const __half* __restrict__ pB,
             void* __restrict__ pC, void* __restrict__ pC2,
             __half* __restrict__ PH1, __half* __restrict__ PH2,
             __half* __restrict__ PH3, __half* __restrict__ PH4,
             const float* __restrict__ Lr) {
    constexpr int LD = (MODE == 0) ? 1024 : (MODE == 1 ? 2048 : 4096);

    const int tid = threadIdx.x;

    int bi, bj, c = 0, k_lo = 0, NT = 16;
    bool isVT = false;
    if constexpr (MODE == 0) {
        const int id = blockIdx.x;
        const int sw = (id & 7) * 24 + (id >> 3);          // 192 = 8*24, bijective
        if (sw < 128) { bi = sw >> 3; bj = sw & 7; }
        else          { int s2 = sw - 128; bi = s2 >> 4; bj = s2 & 15; isVT = true; }
    } else if constexpr (MODE == 1) {
        const int id = blockIdx.x;
        const int sw = (id & 7) * 17 + (id >> 3);          // 136 = 8*17
        int b = (int)((sqrtf(8.0f * sw + 1.0f) - 1.0f) * 0.5f);
        while ((b + 1) * (b + 2) / 2 <= sw) ++b;
        while (b * (b + 1) / 2 > sw) --b;
        bi = b; bj = sw - b * (b + 1) / 2;
    } else {
        // m204 bijective XCD swizzle over 196 blocks (196 = 4*25 + 4*24)
        const int id = blockIdx.x;
        const int xcd = id & 7;
        const int sw = (xcd < 4 ? xcd * 25 : 100 + (xcd - 4) * 24) + (id >> 3);
        bj = sw / 49;
        int x = sw - 49 * bj;
        int nch = 1;
        for (bi = 0; bi < 16; ++bi) {
            nch = (4 * (bi + 1) + 12) / 13;
            if (x < nch) { c = x; break; }
            x -= nch;
        }
        const int full = 4 * (bi + 1);
        k_lo = c * 13;
        NT = min(full - k_lo, 13);
    }

    const __half* A = pA;
    const __half* B = pB;
    if constexpr (MODE == 0) {
        if (isVT) { A = pB + 2097152; B = pA; }   // A = wv (rows 2048.. of wqkv), B = x
    }

    const int brow = bi * 256, bcol = bj * 256;
    const int lane = tid & 63, wid = tid >> 6;
    const int wm = wid >> 2, wn = wid & 3;
    const int lane15 = lane & 15;
    const int kxor = (lane & 7) << 3;
    const int g16 = (lane >> 4) << 3;

    extern __shared__ __half smem[];  // [2][2][256*64]

    const int srow = (wid << 3) + (lane >> 3);                 // 0..63
    const int scol = ((lane & 7) ^ ((lane >> 3) & 7)) << 3;    // swizzled source col

    auto stage_half = [&](const __half* G, int growbase, int kt, int buf, int mat, int half) {
        const __half* src = G + (size_t)(growbase + half * 128 + srow) * LD + kt * 64 + scol;
        __half* dst = &smem[buf * 32768 + mat * 16384 + (half * 128 + (wid << 3)) * 64];
        __builtin_amdgcn_global_load_lds((gas_void*)src, (las_void*)dst, 16, 0, 0);
        __builtin_amdgcn_global_load_lds((gas_void*)(src + (size_t)64 * LD),
                                         (las_void*)(dst + 64 * 64), 16, 0, 0);
    };

    f32x4 acc[8][4] = {};
    f16x8 bfrag[2][4];

    // prologue: tile k_lo {Ba,Bb,Aa,Ab} + tile k_lo+1 {Ba,Bb}
    stage_half(B, bcol, k_lo, 0, 1, 0);
    stage_half(B, bcol, k_lo, 0, 1, 1);
    stage_half(A, brow, k_lo, 0, 0, 0);
    stage_half(A, brow, k_lo, 0, 0, 1);
    if (NT > 1) {
        stage_half(B, bcol, k_lo + 1, 1, 1, 0);
        stage_half(B, bcol, k_lo + 1, 1, 1, 1);
    }

    for (int Tr = 0; Tr < NT; ++Tr) {
        const int Ta = k_lo + Tr;
        const int buf = Tr & 1;
        const __half* Abase = &smem[buf * 32768 + (wm * 128 + lane15) * 64];
        const __half* Bbase = &smem[buf * 32768 + 16384 + (wn * 64 + lane15) * 64];

        // ---- phase 0 ----
        if (Tr < NT - 1) asm volatile("s_waitcnt vmcnt(4)" ::: "memory");
        else             asm volatile("s_waitcnt vmcnt(0)" ::: "memory");
        __builtin_amdgcn_s_barrier();   // tile Tr fully resident for all waves

        {
#pragma unroll
            for (int kk = 0; kk < 2; ++kk)
#pragma unroll
                for (int n = 0; n < 4; ++n)
                    bfrag[kk][n] = ldsr(Bbase + (n * 16) * 64 + ((kk * 32 + g16) ^ kxor));
            f16x8 af[2][2];
#pragma unroll
            for (int mi = 0; mi < 2; ++mi)
#pragma unroll
                for (int kk = 0; kk < 2; ++kk)
                    af[mi][kk] = ldsr(Abase + (mi * 16) * 64 + ((kk * 32 + g16) ^ kxor));
            if (Tr + 1 < NT) stage_half(A, brow, Ta + 1, buf ^ 1, 0, 0);
            asm volatile("s_waitcnt lgkmcnt(0)" ::: "memory");
            __builtin_amdgcn_sched_barrier(0);
            __builtin_amdgcn_s_setprio(1);
#pragma unroll
            for (int mi = 0; mi < 2; ++mi)
#pragma unroll
                for (int n = 0; n < 4; ++n)
#pragma unroll
                    for (int kk = 0; kk < 2; ++kk)
                        acc[mi][n] = __builtin_amdgcn_mfma_f32_16x16x32_f16(
                            af[mi][kk], bfrag[kk][n], acc[mi][n], 0, 0, 0);
            __builtin_amdgcn_s_setprio(0);
            __builtin_amdgcn_s_barrier();
        }

        // ---- phases 1..3 ----
#pragma unroll
        for (int p = 1; p < 4; ++p) {
            f16x8 af[2][2];
#pragma unroll
            for (int mi = 0; mi < 2; ++mi)
#pragma unroll
                for (int kk = 0; kk < 2; ++kk)
                    af[mi][kk] = ldsr(Abase + ((2 * p + mi) * 16) * 64 + ((kk * 32 + g16) ^ kxor));
            if (p == 1)      { if (Tr + 1 < NT) stage_half(A, brow, Ta + 1, buf ^ 1, 0, 1); }
            else if (p == 2) { if (Tr + 2 < NT) stage_half(B, bcol, Ta + 2, buf, 1, 0); }
            else             { if (Tr + 2 < NT) stage_half(B, bcol, Ta + 2, buf, 1, 1); }
            asm volatile("s_waitcnt lgkmcnt(0)" ::: "memory");
            __builtin_amdgcn_sched_barrier(0);
            __builtin_amdgcn_s_setprio(1);
#pragma unroll
            for (int mi = 0; mi < 2; ++mi)
#pragma unroll
                for (int n = 0; n < 4; ++n)
#pragma unroll
                    for (int kk = 0; kk < 2; ++kk)
                        acc[2 * p + mi][n] = __builtin_amdgcn_mfma_f32_16x16x32_f16(
                            af[mi][kk], bfrag[kk][n], acc[2 * p + mi][n], 0, 0, 0);
            __builtin_amdgcn_s_setprio(0);
            __builtin_amdgcn_s_barrier();
        }
    }

    // ---- epilogue ----
    const int r0 = (lane >> 4) << 2;
    if constexpr (MODE == 2) {
        if (c == 0) {
            float* Ct = (float*)pC;
            const bool doScale = (4 * (bi + 1) <= 13);   // single-chunk rows (bi<=2)
#pragma unroll
            for (int m = 0; m < 8; ++m)
#pragma unroll
                for (int r = 0; r < 4; ++r) {
                    const int row = brow + wm * 128 + m * 16 + r0 + r;
                    const float inv = doScale ? 1.0f / (0.9f * Lr[row]) : 1.0f;
#pragma unroll
                    for (int n = 0; n < 4; ++n) {
                        const int col = bcol + wn * 64 + n * 16 + lane15;
                        Ct[(size_t)row * 1024 + col] = acc[m][n][r] * inv;
                    }
                }
        } else {
            __half* Ph = (c == 1) ? PH1 : (c == 2 ? PH2 : (c == 3 ? PH3 : PH4));
#pragma unroll
            for (int m = 0; m < 8; ++m)
#pragma unroll
                for (int n = 0; n < 4; ++n) {
                    const int col = bcol + wn * 64 + n * 16 + lane15;
#pragma unroll
                    for (int r = 0; r < 4; ++r) {
                        const int row = brow + wm * 128 + m * 16 + r0 + r;
                        Ph[(size_t)row * 1024 + col] = __float2half(acc[m][n][r]);
                    }
                }
        }
    } else {
        __half* Ct = (__half*)pC;
        int ldc = (MODE == 1) ? 4096 : 2048;
        const float scl = (MODE == 1) ? 0.03125f : 1.0f;
        if constexpr (MODE == 0) {
            if (isVT) { Ct = (__half*)pC2; ldc = 4096; }
        }
        const bool dz = (MODE == 1) && (bi == bj);   // diag block: zero col > row
#pragma unroll
        for (int m = 0; m < 8; ++m)
#pragma unroll
            for (int n = 0; n < 4; ++n) {
                const int col = bcol + wn * 64 + n * 16 + lane15;
#pragma unroll
                for (int r = 0; r < 4; ++r) {
                    const int row = brow + wm * 128 + m * 16 + r0 + r;
                    float v = acc[m][n][r] * scl;
                    if (dz && col > row) v = 0.0f;
                    Ct[(size_t)row * ldc + col] = __float2half(v);
                }
            }
    }
}

// ---------- split-K merge (rows >= 768) + deferred softmax scaling ----------
__global__ __launch_bounds__(256) void pv_merge_k(float* __restrict__ out,
                                                  const __half* __restrict__ PH1,
                                                  const __half* __restrict__ PH2,
                                                  const __half* __restrict__ PH3,
                                                  const __half* __restrict__ PH4,
                                                  const float* __restrict__ L) {
    const int row = 768 + blockIdx.x;
    const int bi = row >> 8;
    const int nch = (4 * (bi + 1) + 12) / 13;
    const float inv = 1.0f / (0.9f * L[row]);
    const size_t o = (size_t)row * 1024 + threadIdx.x * 4;
    float4 s = *(float4*)(out + o);
    const __half* planes[4] = { PH1, PH2, PH3, PH4 };
#pragma unroll 4
    for (int cc = 1; cc < nch; ++cc) {
        const __half2* p2 = (const __half2*)(planes[cc - 1] + o);
        float2 a = __half22float2(p2[0]);
        float2 b = __half22float2(p2[1]);
        s.x += a.x; s.y += a.y; s.z += b.x; s.w += b.y;
    }
    s.x *= inv; s.y *= inv; s.z *= inv; s.w *= inv;
    *(float4*)(out + o) = s;
}

// ---------- single-sweep deferred softmax: P' = keep * exp(S) (M=0), L[row] = sum(exp) ----------
// Band above the diagonal (to the 256 boundary) already zeroed by the S-GEMM epilogue.
__global__ __launch_bounds__(256) void softdrop_k(__half* __restrict__ SP,
                                                  float* __restrict__ L, int N) {
    const int i = blockIdx.x;
    const int tid = threadIdx.x;
    const int len = i + 1;
    __half* row = SP + (size_t)i * N;

    float l = 0.f;
    const int len8 = len & ~7;
    for (int j = tid * 8; j < len8; j += 2048) {
        int4 pk = *(const int4*)(row + j);
        const __half* hp = (const __half*)&pk;
        __half o8[8];
        const uint32_t base = (uint32_t)i * 4096u + (uint32_t)j;
#pragma unroll
        for (int q = 0; q < 8; ++q) {
            float e = __expf(__half2float(hp[q]));
            l += e;
            o8[q] = keep_bit(base + q) ? __float2half(e) : __float2half(0.0f);
        }
        *(int4*)(row + j) = *(int4*)o8;
    }
    for (int j = len8 + tid; j < len; j += 256) {
        float e = __expf(__half2float(row[j]));
        l += e;
        row[j] = keep_bit((uint32_t)i * 4096u + (uint32_t)j) ? __float2half(e) : __float2half(0.0f);
    }

    for (int off = 1; off < 64; off <<= 1) l += __shfl_xor(l, off);
    __shared__ float ls[4];
    if ((tid & 63) == 0) ls[tid >> 6] = l;
    __syncthreads();
    if (tid == 0) L[i] = ls[0] + ls[1] + ls[2] + ls[3];
}

// ---------- launch ----------
extern "C" void kernel_launch(void* const* d_in, const int* in_sizes, int n_in,
                              void* d_out, int out_size, void* d_ws, size_t ws_size,
                              hipStream_t stream) {
    const float* x  = (const float*)d_in[0];
    const float* wq = (const float*)d_in[1];
    const float* wk = (const float*)d_in[2];
    const float* wv = (const float*)d_in[3];
    float* out = (float*)d_out;
    char* ws = (char*)d_ws;

    const int N = 4096;

    __half* xb   = (__half*)(ws + 0);          // 4096x1024   (8 MB)
    __half* wqkv = (__half*)(ws + 8388608);    // 3072x1024   (6 MB)
    __half* QK   = (__half*)(ws + 14680064);   // 4096x2048   (16 MB), ld=2048
    __half* VT   = (__half*)(ws + 31457280);   // 1024x4096   (8 MB),  ld=4096
    __half* SP   = (__half*)(ws + 48234496);   // 4096x4096   (32 MB)
    float*  Lr   = (float*)(ws + 81788928);    // 4096 f32    (16 KB)
    __half* PH1  = (__half*)(ws + 83886080);   // 4096x1024 f16 (8 MB)
    __half* PH2  = (__half*)(ws + 92274688);
    __half* PH3  = (__half*)(ws + 100663296);
    __half* PH4  = (__half*)(ws + 109051904);  // end 117440512

    __half* Q = QK;             // ld = 2048
    __half* K = QK + 1024;

    auto* g0 = gemm256<0>;
    auto* g1 = gemm256<1>;
    auto* g2 = gemm256<2>;
    (void)hipFuncSetAttribute((const void*)g0, hipFuncAttributeMaxDynamicSharedMemorySize, 131072);
    (void)hipFuncSetAttribute((const void*)g1, hipFuncAttributeMaxDynamicSharedMemorySize, 131072);
    (void)hipFuncSetAttribute((const void*)g2, hipFuncAttributeMaxDynamicSharedMemorySize, 131072);

    cast_all_k<<<3584, 256, 0, stream>>>(x, wq, wk, wv, xb, wqkv);

    // QK projection + native V^T (= wv @ x^T), one dispatch, 192 blocks
    g0<<<192, 512, 131072, stream>>>(xb, wqkv, QK, VT, nullptr, nullptr, nullptr, nullptr, nullptr);

    // S = Q @ K^T * (1/32), triangular 136 blocks; diag blocks zero the band
    g1<<<136, 512, 131072, stream>>>(Q, K, SP, nullptr, nullptr, nullptr, nullptr, nullptr, nullptr);

    // single sweep: P' = keep * exp(S), L[row] = sum exp(S)
    softdrop_k<<<N, 256, 0, stream>>>(SP, Lr, N);

    // PV: balanced causal split-K, 196 blocks (chunks <= 13 tiles, f16 partials)
    g2<<<196, 512, 131072, stream>>>(SP, VT, out, nullptr, PH1, PH2, PH3, PH4, Lr);

    // merge partials + apply 1/(0.9*L) for rows >= 768
    pv_merge_k<<<3328, 256, 0, stream>>>(out, PH1, PH2, PH3, PH4, Lr);
}

// Round 15
// 139.540 us; speedup vs baseline: 1.2574x; 1.0087x over previous
//
#include <hip/hip_runtime.h>
#include <hip/hip_fp16.h>

// ---------- types ----------
typedef __attribute__((ext_vector_type(8))) _Float16 f16x8;
typedef __attribute__((ext_vector_type(4))) float f32x4;

typedef const __attribute__((address_space(1))) void gas_void;
typedef __attribute__((address_space(3))) void las_void;
typedef __attribute__((address_space(3))) const __half las_chalf;

// asm ds_read_b128: opaque to the compiler's waitcnt pass (we manage lgkmcnt)
__device__ __forceinline__ f16x8 ldsr(const __half* p) {
    f16x8 r;
    asm volatile("ds_read_b128 %0, %1" : "=v"(r) : "v"((las_chalf*)p));
    return r;
}

// ---------- threefry2x32, JAX PARTITIONABLE variant ----------
__device__ __forceinline__ uint32_t rotl32(uint32_t x, int d) { return (x << d) | (x >> (32 - d)); }

__device__ __forceinline__ bool keep_bit(uint32_t flat) {
    uint32_t x0 = 0u;
    uint32_t x1 = flat;
    const uint32_t ks0 = 0u, ks1 = 42u, ks2 = 0u ^ 42u ^ 0x1BD11BDAu;
    x0 += ks0; x1 += ks1;
#define TFR(r) { x0 += x1; x1 = rotl32(x1, r); x1 ^= x0; }
    TFR(13) TFR(15) TFR(26) TFR(6)   x0 += ks1; x1 += ks2 + 1u;
    TFR(17) TFR(29) TFR(16) TFR(24)  x0 += ks2; x1 += ks0 + 2u;
    TFR(13) TFR(15) TFR(26) TFR(6)   x0 += ks0; x1 += ks1 + 3u;
    TFR(17) TFR(29) TFR(16) TFR(24)  x0 += ks1; x1 += ks2 + 4u;
    TFR(13) TFR(15) TFR(26) TFR(6)   x0 += ks2; x1 += ks0 + 5u;
#undef TFR
    uint32_t bits = x0 ^ x1;
    float u = __uint_as_float((bits >> 9) | 0x3f800000u) - 1.0f;
    return u < 0.9f;
}

// ---------- all input casts f32 -> f16 in one dispatch (grid 3584) ----------
__global__ __launch_bounds__(256) void cast_all_k(const float* __restrict__ x,
                                                  const float* __restrict__ wq,
                                                  const float* __restrict__ wk,
                                                  const float* __restrict__ wv,
                                                  __half* __restrict__ xb,
                                                  __half* __restrict__ wqkv) {
    const int b = blockIdx.x;
    const float* src;
    __half* dst;
    size_t i;
    if (b < 2048) {
        src = x; dst = xb;
        i = ((size_t)b * 256 + threadIdx.x) * 8;
    } else {
        const int w = (b - 2048) >> 9;
        src = w == 0 ? wq : (w == 1 ? wk : wv);
        dst = wqkv + (size_t)w * 1048576;
        i = (((size_t)((b - 2048) & 511)) * 256 + threadIdx.x) * 8;
    }
    float4 a = *(const float4*)(src + i);
    float4 c = *(const float4*)(src + i + 4);
    __half2 h[4] = { __floats2half2_rn(a.x, a.y), __floats2half2_rn(a.z, a.w),
                     __floats2half2_rn(c.x, c.y), __floats2half2_rn(c.z, c.w) };
    *(int4*)(dst + i) = *(int4*)h;
}

// ============================================================================
// 256x256 8-phase GEMM engine (T1+T2+T3+T4+T5), C = scale * A @ B^T, f16 in.
// 8 waves (2M x 4N), BK=64, LDS 128KB dynamic: [buf(2)][mat(2)][256][64] f16.
// MODE 0 (QKVT): grid 192. sw<128: QK proj (ld 2048); sw>=128: VT = wv @ x^T.
// MODE 1 (S)   : grid 136, triangular decode; diag blocks zero col>row.
// MODE 2 (PV)  : grid 244, balanced causal split-K, chunks <=10 tiles;
//                chunk 0 -> out (rows<512 scaled), chunks 1..6 -> f16 PH[0..5].
// ============================================================================
template <int MODE>
__global__ __launch_bounds__(512, 2)
void gemm256(const __half* __restrict__ pA, const __half* __restrict__ pB,
             void* __restrict__ pC, void* __restrict__ pC2,
             __half* __restrict__ PHbase,
             const float* __restrict__ Lr) {
    constexpr int LD = (MODE == 0) ? 1024 : (MODE == 1 ? 2048 : 4096);

    const int tid = threadIdx.x;

    int bi, bj, c = 0, k_lo = 0, NT = 16;
    bool isVT = false;
    if constexpr (MODE == 0) {
        const int id = blockIdx.x;
        const int sw = (id & 7) * 24 + (id >> 3);          // 192 = 8*24, bijective
        if (sw < 128) { bi = sw >> 3; bj = sw & 7; }
        else          { int s2 = sw - 128; bi = s2 >> 4; bj = s2 & 15; isVT = true; }
    } else if constexpr (MODE == 1) {
        const int id = blockIdx.x;
        const int sw = (id & 7) * 17 + (id >> 3);          // 136 = 8*17
        int b = (int)((sqrtf(8.0f * sw + 1.0f) - 1.0f) * 0.5f);
        while ((b + 1) * (b + 2) / 2 <= sw) ++b;
        while (b * (b + 1) / 2 > sw) --b;
        bi = b; bj = sw - b * (b + 1) / 2;
    } else {
        // m204 bijective XCD swizzle over 244 blocks (244 = 4*31 + 4*30)
        const int id = blockIdx.x;
        const int xcd = id & 7;
        const int idx = id >> 3;
        const int sw = (xcd < 4 ? xcd * 31 : 124 + (xcd - 4) * 30) + idx;
        bj = sw / 61;
        int x = sw - 61 * bj;
        int nch = 1;
        for (bi = 0; bi < 16; ++bi) {
            nch = (4 * (bi + 1) + 9) / 10;
            if (x < nch) { c = x; break; }
            x -= nch;
        }
        const int full = 4 * (bi + 1);
        k_lo = c * 10;
        NT = min(full - k_lo, 10);
    }

    const __half* A = pA;
    const __half* B = pB;
    if constexpr (MODE == 0) {
        if (isVT) { A = pB + 2097152; B = pA; }   // A = wv (rows 2048.. of wqkv), B = x
    }

    const int brow = bi * 256, bcol = bj * 256;
    const int lane = tid & 63, wid = tid >> 6;
    const int wm = wid >> 2, wn = wid & 3;
    const int lane15 = lane & 15;
    const int kxor = (lane & 7) << 3;
    const int g16 = (lane >> 4) << 3;

    extern __shared__ __half smem[];  // [2][2][256*64]

    const int srow = (wid << 3) + (lane >> 3);                 // 0..63
    const int scol = ((lane & 7) ^ ((lane >> 3) & 7)) << 3;    // swizzled source col

    auto stage_half = [&](const __half* G, int growbase, int kt, int buf, int mat, int half) {
        const __half* src = G + (size_t)(growbase + half * 128 + srow) * LD + kt * 64 + scol;
        __half* dst = &smem[buf * 32768 + mat * 16384 + (half * 128 + (wid << 3)) * 64];
        __builtin_amdgcn_global_load_lds((gas_void*)src, (las_void*)dst, 16, 0, 0);
        __builtin_amdgcn_global_load_lds((gas_void*)(src + (size_t)64 * LD),
                                         (las_void*)(dst + 64 * 64), 16, 0, 0);
    };

    f32x4 acc[8][4] = {};
    f16x8 bfrag[2][4];

    // prologue: tile k_lo {Ba,Bb,Aa,Ab} + tile k_lo+1 {Ba,Bb}
    stage_half(B, bcol, k_lo, 0, 1, 0);
    stage_half(B, bcol, k_lo, 0, 1, 1);
    stage_half(A, brow, k_lo, 0, 0, 0);
    stage_half(A, brow, k_lo, 0, 0, 1);
    if (NT > 1) {
        stage_half(B, bcol, k_lo + 1, 1, 1, 0);
        stage_half(B, bcol, k_lo + 1, 1, 1, 1);
    }

    for (int Tr = 0; Tr < NT; ++Tr) {
        const int Ta = k_lo + Tr;
        const int buf = Tr & 1;
        const __half* Abase = &smem[buf * 32768 + (wm * 128 + lane15) * 64];
        const __half* Bbase = &smem[buf * 32768 + 16384 + (wn * 64 + lane15) * 64];

        // ---- phase 0 ----
        if (Tr < NT - 1) asm volatile("s_waitcnt vmcnt(4)" ::: "memory");
        else             asm volatile("s_waitcnt vmcnt(0)" ::: "memory");
        __builtin_amdgcn_s_barrier();   // tile Tr fully resident for all waves

        {
#pragma unroll
            for (int kk = 0; kk < 2; ++kk)
#pragma unroll
                for (int n = 0; n < 4; ++n)
                    bfrag[kk][n] = ldsr(Bbase + (n * 16) * 64 + ((kk * 32 + g16) ^ kxor));
            f16x8 af[2][2];
#pragma unroll
            for (int mi = 0; mi < 2; ++mi)
#pragma unroll
                for (int kk = 0; kk < 2; ++kk)
                    af[mi][kk] = ldsr(Abase + (mi * 16) * 64 + ((kk * 32 + g16) ^ kxor));
            if (Tr + 1 < NT) stage_half(A, brow, Ta + 1, buf ^ 1, 0, 0);
            asm volatile("s_waitcnt lgkmcnt(0)" ::: "memory");
            __builtin_amdgcn_sched_barrier(0);
            __builtin_amdgcn_s_setprio(1);
#pragma unroll
            for (int mi = 0; mi < 2; ++mi)
#pragma unroll
                for (int n = 0; n < 4; ++n)
#pragma unroll
                    for (int kk = 0; kk < 2; ++kk)
                        acc[mi][n] = __builtin_amdgcn_mfma_f32_16x16x32_f16(
                            af[mi][kk], bfrag[kk][n], acc[mi][n], 0, 0, 0);
            __builtin_amdgcn_s_setprio(0);
            __builtin_amdgcn_s_barrier();
        }

        // ---- phases 1..3 ----
#pragma unroll
        for (int p = 1; p < 4; ++p) {
            f16x8 af[2][2];
#pragma unroll
            for (int mi = 0; mi < 2; ++mi)
#pragma unroll
                for (int kk = 0; kk < 2; ++kk)
                    af[mi][kk] = ldsr(Abase + ((2 * p + mi) * 16) * 64 + ((kk * 32 + g16) ^ kxor));
            if (p == 1)      { if (Tr + 1 < NT) stage_half(A, brow, Ta + 1, buf ^ 1, 0, 1); }
            else if (p == 2) { if (Tr + 2 < NT) stage_half(B, bcol, Ta + 2, buf, 1, 0); }
            else             { if (Tr + 2 < NT) stage_half(B, bcol, Ta + 2, buf, 1, 1); }
            asm volatile("s_waitcnt lgkmcnt(0)" ::: "memory");
            __builtin_amdgcn_sched_barrier(0);
            __builtin_amdgcn_s_setprio(1);
#pragma unroll
            for (int mi = 0; mi < 2; ++mi)
#pragma unroll
                for (int n = 0; n < 4; ++n)
#pragma unroll
                    for (int kk = 0; kk < 2; ++kk)
                        acc[2 * p + mi][n] = __builtin_amdgcn_mfma_f32_16x16x32_f16(
                            af[mi][kk], bfrag[kk][n], acc[2 * p + mi][n], 0, 0, 0);
            __builtin_amdgcn_s_setprio(0);
            __builtin_amdgcn_s_barrier();
        }
    }

    // ---- epilogue ----
    const int r0 = (lane >> 4) << 2;
    if constexpr (MODE == 2) {
        if (c == 0) {
            float* Ct = (float*)pC;
            const bool doScale = (4 * (bi + 1) <= 10);   // single-chunk rows (bi<=1)
#pragma unroll
            for (int m = 0; m < 8; ++m)
#pragma unroll
                for (int r = 0; r < 4; ++r) {
                    const int row = brow + wm * 128 + m * 16 + r0 + r;
                    const float inv = doScale ? 1.0f / (0.9f * Lr[row]) : 1.0f;
#pragma unroll
                    for (int n = 0; n < 4; ++n) {
                        const int col = bcol + wn * 64 + n * 16 + lane15;
                        Ct[(size_t)row * 1024 + col] = acc[m][n][r] * inv;
                    }
                }
        } else {
            __half* Ph = PHbase + (size_t)(c - 1) * 4194304;   // 4096*1024 f16 planes
#pragma unroll
            for (int m = 0; m < 8; ++m)
#pragma unroll
                for (int n = 0; n < 4; ++n) {
                    const int col = bcol + wn * 64 + n * 16 + lane15;
#pragma unroll
                    for (int r = 0; r < 4; ++r) {
                        const int row = brow + wm * 128 + m * 16 + r0 + r;
                        Ph[(size_t)row * 1024 + col] = __float2half(acc[m][n][r]);
                    }
                }
        }
    } else {
        __half* Ct = (__half*)pC;
        int ldc = (MODE == 1) ? 4096 : 2048;
        const float scl = (MODE == 1) ? 0.03125f : 1.0f;
        if constexpr (MODE == 0) {
            if (isVT) { Ct = (__half*)pC2; ldc = 4096; }
        }
        const bool dz = (MODE == 1) && (bi == bj);   // diag block: zero col > row
#pragma unroll
        for (int m = 0; m < 8; ++m)
#pragma unroll
            for (int n = 0; n < 4; ++n) {
                const int col = bcol + wn * 64 + n * 16 + lane15;
#pragma unroll
                for (int r = 0; r < 4; ++r) {
                    const int row = brow + wm * 128 + m * 16 + r0 + r;
                    float v = acc[m][n][r] * scl;
                    if (dz && col > row) v = 0.0f;
                    Ct[(size_t)row * ldc + col] = __float2half(v);
                }
            }
    }
}

// ---------- split-K merge (rows >= 512) + deferred softmax scaling ----------
__global__ __launch_bounds__(256) void pv_merge_k(float* __restrict__ out,
                                                  const __half* __restrict__ PHbase,
                                                  const float* __restrict__ L) {
    const int row = 512 + blockIdx.x;
    const int bi = row >> 8;
    const int nch = (4 * (bi + 1) + 9) / 10;
    const float inv = 1.0f / (0.9f * L[row]);
    const size_t o = (size_t)row * 1024 + threadIdx.x * 4;
    float4 s = *(float4*)(out + o);
#pragma unroll 6
    for (int cc = 1; cc < nch; ++cc) {
        const __half2* p2 = (const __half2*)(PHbase + (size_t)(cc - 1) * 4194304 + o);
        float2 a = __half22float2(p2[0]);
        float2 b = __half22float2(p2[1]);
        s.x += a.x; s.y += a.y; s.z += b.x; s.w += b.y;
    }
    s.x *= inv; s.y *= inv; s.z *= inv; s.w *= inv;
    *(float4*)(out + o) = s;
}

// ---------- single-sweep deferred softmax: P' = keep * exp(S) (M=0), L[row] = sum(exp) ----------
// Band above the diagonal (to the 256 boundary) already zeroed by the S-GEMM epilogue.
__global__ __launch_bounds__(256) void softdrop_k(__half* __restrict__ SP,
                                                  float* __restrict__ L, int N) {
    const int i = blockIdx.x;
    const int tid = threadIdx.x;
    const int len = i + 1;
    __half* row = SP + (size_t)i * N;

    float l = 0.f;
    const int len8 = len & ~7;
    for (int j = tid * 8; j < len8; j += 2048) {
        int4 pk = *(const int4*)(row + j);
        const __half* hp = (const __half*)&pk;
        __half o8[8];
        const uint32_t base = (uint32_t)i * 4096u + (uint32_t)j;
#pragma unroll
        for (int q = 0; q < 8; ++q) {
            float e = __expf(__half2float(hp[q]));
            l += e;
            o8[q] = keep_bit(base + q) ? __float2half(e) : __float2half(0.0f);
        }
        *(int4*)(row + j) = *(int4*)o8;
    }
    for (int j = len8 + tid; j < len; j += 256) {
        float e = __expf(__half2float(row[j]));
        l += e;
        row[j] = keep_bit((uint32_t)i * 4096u + (uint32_t)j) ? __float2half(e) : __float2half(0.0f);
    }

    for (int off = 1; off < 64; off <<= 1) l += __shfl_xor(l, off);
    __shared__ float ls[4];
    if ((tid & 63) == 0) ls[tid >> 6] = l;
    __syncthreads();
    if (tid == 0) L[i] = ls[0] + ls[1] + ls[2] + ls[3];
}

// ---------- launch ----------
extern "C" void kernel_launch(void* const* d_in, const int* in_sizes, int n_in,
                              void* d_out, int out_size, void* d_ws, size_t ws_size,
                              hipStream_t stream) {
    const float* x  = (const float*)d_in[0];
    const float* wq = (const float*)d_in[1];
    const float* wk = (const float*)d_in[2];
    const float* wv = (const float*)d_in[3];
    float* out = (float*)d_out;
    char* ws = (char*)d_ws;

    const int N = 4096;

    __half* xb   = (__half*)(ws + 0);          // 4096x1024   (8 MB)
    __half* wqkv = (__half*)(ws + 8388608);    // 3072x1024   (6 MB)
    __half* QK   = (__half*)(ws + 14680064);   // 4096x2048   (16 MB), ld=2048
    __half* VT   = (__half*)(ws + 31457280);   // 1024x4096   (8 MB),  ld=4096
    __half* SP   = (__half*)(ws + 48234496);   // 4096x4096   (32 MB)
    float*  Lr   = (float*)(ws + 81788928);    // 4096 f32    (16 KB)
    __half* PH   = (__half*)(ws + 83886080);   // 6 planes x 4096x1024 f16 (48 MB), end 134217728

    __half* Q = QK;             // ld = 2048
    __half* K = QK + 1024;

    auto* g0 = gemm256<0>;
    auto* g1 = gemm256<1>;
    auto* g2 = gemm256<2>;
    (void)hipFuncSetAttribute((const void*)g0, hipFuncAttributeMaxDynamicSharedMemorySize, 131072);
    (void)hipFuncSetAttribute((const void*)g1, hipFuncAttributeMaxDynamicSharedMemorySize, 131072);
    (void)hipFuncSetAttribute((const void*)g2, hipFuncAttributeMaxDynamicSharedMemorySize, 131072);

    cast_all_k<<<3584, 256, 0, stream>>>(x, wq, wk, wv, xb, wqkv);

    // QK projection + native V^T (= wv @ x^T), one dispatch, 192 blocks
    g0<<<192, 512, 131072, stream>>>(xb, wqkv, QK, VT, nullptr, nullptr);

    // S = Q @ K^T * (1/32), triangular 136 blocks; diag blocks zero the band
    g1<<<136, 512, 131072, stream>>>(Q, K, SP, nullptr, nullptr, nullptr);

    // single sweep: P' = keep * exp(S), L[row] = sum exp(S)
    softdrop_k<<<N, 256, 0, stream>>>(SP, Lr, N);

    // PV: balanced causal split-K, 244 blocks (chunks <= 10 tiles, f16 partials)
    g2<<<244, 512, 131072, stream>>>(SP, VT, out, nullptr, PH, Lr);

    // merge partials + apply 1/(0.9*L) for rows >= 512
    pv_merge_k<<<3584, 256, 0, stream>>>(out, PH, Lr);
}